// Round 7
// baseline (209.251 us; speedup 1.0000x reference)
//
#include <hip/hip_runtime.h>
#include <math.h>

#define NN 20000     // nodes
#define NE 320000    // edges
#define NR 500       // relations
#define EMBD 256
#define D4 64
#define BQ 32        // batch
#define TOT (2 * NN)     // bins per partition (in | out)
#define NPART 8          // CSR partitions (~XCDs)
#define TOT2 (NPART * TOT)
#define NB2 ((TOT2 + 1023) / 1024)   // 313 scan blocks
#define NBLK_BN 448  // buildBn data blocks

typedef __attribute__((ext_vector_type(8))) short bf16x8;
typedef __attribute__((ext_vector_type(4))) float f32x4;

__device__ __forceinline__ unsigned short f2bf(float x)
{
    unsigned int u = __float_as_uint(x);
    unsigned int r = (u + 0x7fffu + ((u >> 16) & 1u)) >> 16;   // RNE
    return (unsigned short)r;
}

// ---------------- weight pack + folded param kernel ----------------
__global__ void k_buildBn(const float* __restrict__ W_O1, const float* __restrict__ W_I1,
                          const float* __restrict__ W_S1, const float* __restrict__ Wr1,
                          const float* __restrict__ W_O2, const float* __restrict__ W_I2,
                          const float* __restrict__ W_S2,
                          unsigned short* __restrict__ Bn1, unsigned short* __restrict__ Bn2,
                          const float* __restrict__ bO1, const float* __restrict__ bI1,
                          const float* __restrict__ bS1,
                          const float* __restrict__ g1, const float* __restrict__ bb1,
                          const float* __restrict__ m1, const float* __restrict__ v1,
                          const float* __restrict__ bO2, const float* __restrict__ bI2,
                          const float* __restrict__ bS2,
                          const float* __restrict__ g2, const float* __restrict__ bb2,
                          const float* __restrict__ m2, const float* __restrict__ v2,
                          float* __restrict__ s1, float* __restrict__ t1,
                          float* __restrict__ s2, float* __restrict__ t2)
{
    int b = blockIdx.x;
    if (b >= NBLK_BN) {
        int i = (b - NBLK_BN) * 256 + threadIdx.x;   // [0,512)
        if (i < 64) {
            float rsg = g1[i] / sqrtf(v1[i] + 1e-5f);
            s1[i] = rsg * (1.f / 3.f);
            t1[i] = ((bO1[i] + bI1[i] + bS1[i]) * (1.f / 3.f) - m1[i]) * rsg + bb1[i];
        } else if (i < 320) {
            int n = i - 64;
            float rsg = g2[n] / sqrtf(v2[n] + 1e-5f);
            s2[n] = rsg * (1.f / 3.f);
            t2[n] = ((bO2[n] + bI2[n] + bS2[n]) * (1.f / 3.f) - m2[n]) * rsg + bb2[n];
        }
        return;
    }
    int id = b * 256 + threadIdx.x;
    if (id < 256 * 256) {
        int n = id >> 8, k = id & 255;
        float v;
        if (n < 64)       v = W_O1[n * 256 + k];
        else if (n < 128) v = W_I1[(n - 64) * 256 + k];
        else if (n < 192) v = W_S1[(n - 128) * 256 + k];
        else              v = Wr1[(n - 192) * 256 + k];
        Bn1[id] = f2bf(v);
    } else {
        int id2 = id - 256 * 256;
        if (id2 < 256 * 192) {
            int n = id2 / 192, k = id2 - n * 192;
            float v;
            if (k < 64)       v = W_O2[n * 64 + k];
            else if (k < 128) v = W_I2[n * 64 + (k - 64)];
            else              v = W_S2[n * 64 + (k - 128)];
            Bn2[id2] = f2bf(v);
        }
    }
}

// ---------------- CSR build (partitioned) ----------------
// cnt2[p*TOT + bin], bin = dst (in) or NN+src (out); partition p = blockIdx&7

__global__ void k_hist(const int* __restrict__ src, const int* __restrict__ dst,
                       int* __restrict__ cnt2)
{
    int i = blockIdx.x * 256 + threadIdx.x;
    int part = blockIdx.x & (NPART - 1);
    if (i < NE) {
        int base = part * TOT;
        atomicAdd(&cnt2[base + dst[i]], 1);
        atomicAdd(&cnt2[base + NN + src[i]], 1);
    }
}

// phase A: per-block (1024 elems) sum -> bsum
__global__ __launch_bounds__(256) void k_scanA(const int* __restrict__ cnt,
                                               int* __restrict__ bsum)
{
    __shared__ int lds[256];
    int t = threadIdx.x;
    int base = blockIdx.x * 1024 + t * 4;
    int s = 0;
    if (base + 3 < TOT2) {
        int4 v = *(const int4*)(cnt + base);
        s = v.x + v.y + v.z + v.w;
    } else {
        for (int c = 0; c < 4; ++c) { int i = base + c; if (i < TOT2) s += cnt[i]; }
    }
    lds[t] = s;
    __syncthreads();
    for (int d = 128; d > 0; d >>= 1) {
        if (t < d) lds[t] += lds[t + d];
        __syncthreads();
    }
    if (t == 0) bsum[blockIdx.x] = lds[0];
}

// phase B: one wave exclusive-scans nb block sums in place (chunked)
__global__ __launch_bounds__(64) void k_scanB(int* __restrict__ bsum, int nb)
{
    int t = threadIdx.x;
    int carry = 0;
    for (int c = 0; c < nb; c += 64) {
        int i = c + t;
        int v = (i < nb) ? bsum[i] : 0;
        int vin = v;
#pragma unroll
        for (int d = 1; d < 64; d <<= 1) {
            int u = __shfl_up(v, d, 64);
            if (t >= d) v += u;
        }
        if (i < nb) bsum[i] = (v - vin) + carry;
        carry += __shfl(v, 63, 64);
    }
}

// phase C: local exclusive scan + block offset -> offc2, cur2
__global__ __launch_bounds__(256) void k_scanC(const int* __restrict__ cnt,
                                               const int* __restrict__ bsum,
                                               int* __restrict__ offc,
                                               int* __restrict__ cur)
{
    __shared__ int lds[256];
    int t = threadIdx.x;
    int base = blockIdx.x * 1024 + t * 4;
    int e0 = 0, e1 = 0, e2 = 0, e3 = 0;
    if (base + 3 < TOT2) {
        int4 v = *(const int4*)(cnt + base);
        e0 = v.x; e1 = v.y; e2 = v.z; e3 = v.w;
    } else {
        if (base + 0 < TOT2) e0 = cnt[base + 0];
        if (base + 1 < TOT2) e1 = cnt[base + 1];
        if (base + 2 < TOT2) e2 = cnt[base + 2];
        if (base + 3 < TOT2) e3 = cnt[base + 3];
    }
    int s = e0 + e1 + e2 + e3;
    lds[t] = s;
    __syncthreads();
    for (int d = 1; d < 256; d <<= 1) {
        int u = (t >= d) ? lds[t - d] : 0;
        __syncthreads();
        lds[t] += u;
        __syncthreads();
    }
    int run = lds[t] - s + bsum[blockIdx.x];
    if (base + 3 < TOT2) {
        int4 o = make_int4(run, run + e0, run + e0 + e1, run + e0 + e1 + e2);
        *(int4*)(offc + base) = o;
        *(int4*)(cur + base) = o;
    } else {
        int r = run;
        if (base + 0 < TOT2) { offc[base + 0] = r; cur[base + 0] = r; r += e0; }
        if (base + 1 < TOT2) { offc[base + 1] = r; cur[base + 1] = r; r += e1; }
        if (base + 2 < TOT2) { offc[base + 2] = r; cur[base + 2] = r; r += e2; }
        if (base + 3 < TOT2) { offc[base + 3] = r; cur[base + 3] = r; r += e3; }
    }
    if (blockIdx.x == 0 && t == 0) offc[TOT2] = 2 * NE;   // grand total is fixed
}

// scatter PACKED records (other | evid<<15) into partitioned R
__global__ void k_scatter(const int* __restrict__ src, const int* __restrict__ dst,
                          const int* __restrict__ evid,
                          int* __restrict__ cur, unsigned* __restrict__ R)
{
    int e = blockIdx.x * 256 + threadIdx.x;
    int part = blockIdx.x & (NPART - 1);
    if (e >= NE) return;
    int s = src[e], d = dst[e];
    unsigned rv = (unsigned)evid[e] << 15;
    int base = part * TOT;
    int p = atomicAdd(&cur[base + d], 1);
    R[p] = (unsigned)s | rv;
    int q = atomicAdd(&cur[base + NN + s], 1);
    R[q] = (unsigned)d | rv;
}

// ---------------- MFMA bf16 GEMM: C = A @ Bn^T ----------------
__global__ __launch_bounds__(256) void gemm_mfma(
    const float* __restrict__ A, int M, int K, int lda,
    const unsigned short* __restrict__ Bn,
    float* __restrict__ C, int ldc, int mode,
    const float* __restrict__ sv, const float* __restrict__ tv,
    const float* __restrict__ node_embs, const int* __restrict__ flag)
{
    __shared__ unsigned short As[64 * 72];
    __shared__ unsigned short Bs[64 * 72];
    const int t = threadIdx.x;
    const int m0 = blockIdx.x * 64, n0 = blockIdx.y * 64;
    const int lane = t & 63, wave = t >> 6;
    const int wr = wave >> 1, wc = wave & 1;
    const int lrow = lane & 15, lkg = lane >> 4;

    f32x4 acc[2][2] = {};

    for (int kb = 0; kb < K; kb += 64) {
#pragma unroll
        for (int it = 0; it < 4; ++it) {
            int idx = t + it * 256;
            int kq = idx & 15;
            int row = idx >> 4;
            int gm = m0 + row;
            float4 a = make_float4(0.f, 0.f, 0.f, 0.f);
            if (gm < M) a = *(const float4*)(A + (size_t)gm * lda + kb + 4 * kq);
            unsigned int p0 = (unsigned int)f2bf(a.x) | ((unsigned int)f2bf(a.y) << 16);
            unsigned int p1 = (unsigned int)f2bf(a.z) | ((unsigned int)f2bf(a.w) << 16);
            *(uint2*)&As[row * 72 + 4 * kq] = make_uint2(p0, p1);
        }
#pragma unroll
        for (int it = 0; it < 2; ++it) {
            int idx = t + it * 256;
            int ko = idx & 7;
            int row = idx >> 3;
            uint4 b = *(const uint4*)(Bn + (size_t)(n0 + row) * K + kb + 8 * ko);
            *(uint4*)&Bs[row * 72 + 8 * ko] = b;
        }
        __syncthreads();
#pragma unroll
        for (int ks = 0; ks < 2; ++ks) {
            int k0 = ks * 32 + lkg * 8;
            bf16x8 af0 = *(const bf16x8*)&As[(wr * 32 + lrow) * 72 + k0];
            bf16x8 af1 = *(const bf16x8*)&As[(wr * 32 + 16 + lrow) * 72 + k0];
            bf16x8 bf0 = *(const bf16x8*)&Bs[(wc * 32 + lrow) * 72 + k0];
            bf16x8 bf1 = *(const bf16x8*)&Bs[(wc * 32 + 16 + lrow) * 72 + k0];
            acc[0][0] = __builtin_amdgcn_mfma_f32_16x16x32_bf16(af0, bf0, acc[0][0], 0, 0, 0);
            acc[0][1] = __builtin_amdgcn_mfma_f32_16x16x32_bf16(af0, bf1, acc[0][1], 0, 0, 0);
            acc[1][0] = __builtin_amdgcn_mfma_f32_16x16x32_bf16(af1, bf0, acc[1][0], 0, 0, 0);
            acc[1][1] = __builtin_amdgcn_mfma_f32_16x16x32_bf16(af1, bf1, acc[1][1], 0, 0, 0);
        }
        __syncthreads();
    }

#pragma unroll
    for (int m = 0; m < 2; ++m) {
#pragma unroll
        for (int r = 0; r < 4; ++r) {
            int gm = m0 + wr * 32 + m * 16 + lkg * 4 + r;
            if (gm >= M) continue;
#pragma unroll
            for (int n = 0; n < 2; ++n) {
                int gn = n0 + wc * 32 + n * 16 + lrow;
                float v = acc[m][n][r];
                if (mode == 0) {
                    C[(size_t)gm * ldc + gn] = v;
                } else if (mode == 1) {
                    float val = (gn >= 192) ? tanhf(v + sv[gn - 192]) : v;
                    C[(size_t)gm * ldc + gn] = val;
                } else {
                    float val = tanhf(v * sv[gn] + tv[gn]);
                    if (flag[0] == 0) val = node_embs[(size_t)gm * EMBD + gn];
                    C[(size_t)gm * EMBD + gn] = val;
                }
            }
        }
    }
}

// ---------------- CSR gather: merged-direction, 16-range concat ----------------
// Wave = 1 node. 16 ranges (8 partitions x 2 dirs) concatenated in-register;
// records fetched lane-per-slot (dir packed in bit 31), rows processed by
// 16-lane groups 4-at-a-time (float4/lane = 256B/row per instruction).

__device__ __forceinline__ void gnode(
    const int* __restrict__ offc2, const unsigned* __restrict__ R,
    int n, int lane,
    const float* __restrict__ TAB, int ldt, int toff0, int toff1,
    const float* __restrict__ E1, int eoff0, int eoff1,
    float4& accO, float4& accI, float& invdi, float& invdo)
{
    const int g = lane >> 4, q = lane & 15;
    const int r16 = lane & 15;                 // range id: dir*8 + part
    const int part = r16 & 7, dir0 = r16 >> 3;
    const int bin = dir0 * NN + n;
    const int s = offc2[part * TOT + bin];
    const int e = offc2[part * TOT + bin + 1];
    const int len = e - s;
    int pre = len;
#pragma unroll
    for (int dd = 1; dd < 16; dd <<= 1) {
        int u = __shfl_up(pre, dd, 16);
        if (r16 >= dd) pre += u;
    }
    const int T   = __shfl(pre, 15, 16);
    const int dIn = __shfl(pre, 7, 16);
    const int excl = pre - len;
    invdi = 1.f / fmaxf((float)dIn, 1.f);
    invdo = 1.f / fmaxf((float)(T - dIn), 1.f);

    for (int base = 0; base < T; base += 64) {
        int rem = T - base; if (rem > 64) rem = 64;
        int i = base + lane;
        int pos = 0; unsigned hidir = 0;
#pragma unroll
        for (int rr = 0; rr < 16; ++rr) {
            int ex = __shfl(excl, rr, 16);
            int ln = __shfl(len, rr, 16);
            int ss = __shfl(s, rr, 16);
            if (i >= ex && i < ex + ln) { pos = ss + (i - ex); hidir = (unsigned)(rr >> 3) << 31; }
        }
        unsigned rec = (lane < rem) ? (R[pos] | hidir) : 0u;

#define GQ_ADDR(RV, AP, EP)                                                          \
        {   int dr = (int)((RV) >> 31);                                              \
            AP = (const float4*)(TAB + (size_t)((RV) & 0x7FFFu) * ldt +              \
                                 (dr ? toff1 : toff0) + 4 * q);                      \
            EP = (const float4*)(E1 + (size_t)(((RV) >> 15) & 0x1FFu) * 256 +        \
                                 (dr ? eoff1 : eoff0) + 4 * q); }
#define GQ_ACC(RV, AV, EV)                                                           \
        {   if ((int)((RV) >> 31)) {                                                 \
                accI.x += AV.x - EV.x; accI.y += AV.y - EV.y;                        \
                accI.z += AV.z - EV.z; accI.w += AV.w - EV.w;                        \
            } else {                                                                 \
                accO.x += AV.x - EV.x; accO.y += AV.y - EV.y;                        \
                accO.z += AV.z - EV.z; accO.w += AV.w - EV.w; } }

        int i4 = 0;
        for (; 4 * i4 + 15 < rem; i4 += 4) {
            unsigned ra = __shfl(rec, 4 * i4 + g, 64);
            unsigned rb = __shfl(rec, 4 * i4 + 4 + g, 64);
            unsigned rc = __shfl(rec, 4 * i4 + 8 + g, 64);
            unsigned rd = __shfl(rec, 4 * i4 + 12 + g, 64);
            const float4 *pa0, *pe0, *pa1, *pe1, *pa2, *pe2, *pa3, *pe3;
            GQ_ADDR(ra, pa0, pe0); GQ_ADDR(rb, pa1, pe1);
            GQ_ADDR(rc, pa2, pe2); GQ_ADDR(rd, pa3, pe3);
            float4 a0 = *pa0, e0v = *pe0, a1 = *pa1, e1v = *pe1;
            float4 a2 = *pa2, e2v = *pe2, a3 = *pa3, e3v = *pe3;
            GQ_ACC(ra, a0, e0v); GQ_ACC(rb, a1, e1v);
            GQ_ACC(rc, a2, e2v); GQ_ACC(rd, a3, e3v);
        }
        for (; 4 * i4 < rem; ++i4) {
            int sl = 4 * i4 + g;
            unsigned rr = __shfl(rec, sl < rem ? sl : 0, 64);
            if (sl < rem) {
                const float4 *pa, *pe;
                GQ_ADDR(rr, pa, pe);
                float4 a = *pa, ev = *pe;
                GQ_ACC(rr, a, ev);
            }
        }
#undef GQ_ADDR
#undef GQ_ACC
    }
}

__device__ __forceinline__ void xreduce(float4& v)
{
    v.x += __shfl_xor(v.x, 16, 64); v.y += __shfl_xor(v.y, 16, 64);
    v.z += __shfl_xor(v.z, 16, 64); v.w += __shfl_xor(v.w, 16, 64);
    v.x += __shfl_xor(v.x, 32, 64); v.y += __shfl_xor(v.y, 32, 64);
    v.z += __shfl_xor(v.z, 32, 64); v.w += __shfl_xor(v.w, 32, 64);
}

// layer 1 fused with combine: h1 = tanh((accO/deg_in + accI/deg_out + hS1raw)*s1 + t1)
__global__ __launch_bounds__(256) void k_gather1(
    const int* __restrict__ offc2, const unsigned* __restrict__ R,
    const float* __restrict__ C1, const float* __restrict__ E1,
    const float* __restrict__ s1, const float* __restrict__ t1,
    float* __restrict__ A2)
{
    int n = blockIdx.x * 4 + (threadIdx.x >> 6);
    if (n >= NN) return;
    int lane = threadIdx.x & 63, g = lane >> 4, q = lane & 15;
    float4 accO = make_float4(0.f, 0.f, 0.f, 0.f);
    float4 accI = make_float4(0.f, 0.f, 0.f, 0.f);
    float di, dh;
    gnode(offc2, R, n, lane, C1, 192, 0, 64, E1, 0, 64, accO, accI, di, dh);
    xreduce(accO);
    xreduce(accI);
    if (g == 0) {
        float4 hs = *(const float4*)(C1 + (size_t)n * 192 + 128 + 4 * q);
        float4 sv = *(const float4*)(s1 + 4 * q);
        float4 tv = *(const float4*)(t1 + 4 * q);
        float4 o;
        o.x = tanhf((accO.x * di + accI.x * dh + hs.x) * sv.x + tv.x);
        o.y = tanhf((accO.y * di + accI.y * dh + hs.y) * sv.y + tv.y);
        o.z = tanhf((accO.z * di + accI.z * dh + hs.z) * sv.z + tv.z);
        o.w = tanhf((accO.w * di + accI.w * dh + hs.w) * sv.w + tv.w);
        *(float4*)(A2 + (size_t)n * 192 + 128 + 4 * q) = o;
    }
}

// layer 2: both dirs read h1 (A2 cols[128,192)) minus er1 (E1 cols[192,256))
__global__ __launch_bounds__(256) void k_gather2(
    const int* __restrict__ offc2, const unsigned* __restrict__ R,
    const float* __restrict__ A2r, const float* __restrict__ E1,
    float* __restrict__ A2w)
{
    int n = blockIdx.x * 4 + (threadIdx.x >> 6);
    if (n >= NN) return;
    int lane = threadIdx.x & 63, g = lane >> 4, q = lane & 15;
    float4 accO = make_float4(0.f, 0.f, 0.f, 0.f);
    float4 accI = make_float4(0.f, 0.f, 0.f, 0.f);
    float di, dh;
    gnode(offc2, R, n, lane, A2r, 192, 128, 128, E1, 192, 192, accO, accI, di, dh);
    xreduce(accO);
    xreduce(accI);
    if (g == 0) {
        float4 o0, o1;
        o0.x = accO.x * di; o0.y = accO.y * di; o0.z = accO.z * di; o0.w = accO.w * di;
        o1.x = accI.x * dh; o1.y = accI.y * dh; o1.z = accI.z * dh; o1.w = accI.w * dh;
        *(float4*)(A2w + (size_t)n * 192 + 4 * q) = o0;
        *(float4*)(A2w + (size_t)n * 192 + 64 + 4 * q) = o1;
    }
}

// ---------------- scoring ----------------
__global__ __launch_bounds__(64) void k_rels(
    const float* __restrict__ edge_embs,
    const float* __restrict__ Wr1, const float* __restrict__ br1,
    const float* __restrict__ Wr2, const float* __restrict__ br2,
    const int* __restrict__ hids, const int* __restrict__ rids, const int* __restrict__ tids,
    const int* __restrict__ is_head, const float* __restrict__ hn,
    float* __restrict__ tvec)
{
    __shared__ float e_s[256];
    __shared__ float m_s[64];
    int b = blockIdx.x, o = threadIdx.x;
    int rid = rids[b];
#pragma unroll
    for (int q = 0; q < 4; ++q) e_s[o + 64 * q] = edge_embs[(size_t)rid * 256 + o + 64 * q];
    __syncthreads();
    float acc = br1[o];
    for (int k = 0; k < 256; ++k) acc = fmaf(e_s[k], Wr1[o * 256 + k], acc);
    m_s[o] = fmaxf(acc, 0.f);
    __syncthreads();
    int ih = is_head[0];
    int nid = ih ? tids[b] : hids[b];
#pragma unroll
    for (int q = 0; q < 4; ++q) {
        int n = o + 64 * q;
        float r = br2[n];
        for (int jj = 0; jj < 64; ++jj) r = fmaf(m_s[jj], Wr2[n * 64 + jj], r);
        float hv = hn[(size_t)nid * 256 + n];
        tvec[b * 256 + n] = ih ? (hv - r) : (hv + r);
    }
}

__global__ __launch_bounds__(256) void k_score(
    const float* __restrict__ hn, const float* __restrict__ tvec,
    float* __restrict__ score)
{
    int p = blockIdx.x * 4 + (threadIdx.x >> 6);
    if (p >= BQ * (NN / BQ)) return;
    int l = threadIdx.x & 63;
    int b = p / (NN / BQ);
    int j = p - b * (NN / BQ);
    int idx = (b * NN + 32 * j) / BQ;   // faithful repeat_interleave indexing
    float ssum = 0.f;
#pragma unroll
    for (int q = 0; q < 4; ++q) {
        float df = hn[(size_t)idx * 256 + l + 64 * q] - tvec[b * 256 + l + 64 * q];
        ssum = fmaf(df, df, ssum);
    }
#pragma unroll
    for (int off = 32; off >= 1; off >>= 1) ssum += __shfl_xor(ssum, off, 64);
    float dist = sqrtf(ssum);
    float sc = 1.f / (1.f + expf(dist - 12.f));
    if (l < 32) score[(size_t)b * NN + 32 * j + l] = sc;
}

// ---------------- launch ----------------
extern "C" void kernel_launch(void* const* d_in, const int* in_sizes, int n_in,
                              void* d_out, int out_size, void* d_ws, size_t ws_size,
                              hipStream_t stream)
{
    const float* node_embs = (const float*)d_in[0];
    const float* edge_embs = (const float*)d_in[1];
    const float* W_O1 = (const float*)d_in[2];  const float* b_O1 = (const float*)d_in[3];
    const float* W_I1 = (const float*)d_in[4];  const float* b_I1 = (const float*)d_in[5];
    const float* W_S1 = (const float*)d_in[6];  const float* b_S1 = (const float*)d_in[7];
    const float* bn1_g = (const float*)d_in[8]; const float* bn1_b = (const float*)d_in[9];
    const float* bn1_m = (const float*)d_in[10];const float* bn1_v = (const float*)d_in[11];
    const float* Wr1 = (const float*)d_in[12];  const float* br1 = (const float*)d_in[13];
    const float* W_O2 = (const float*)d_in[14]; const float* b_O2 = (const float*)d_in[15];
    const float* W_I2 = (const float*)d_in[16]; const float* b_I2 = (const float*)d_in[17];
    const float* W_S2 = (const float*)d_in[18]; const float* b_S2 = (const float*)d_in[19];
    const float* bn2_g = (const float*)d_in[20];const float* bn2_b = (const float*)d_in[21];
    const float* bn2_m = (const float*)d_in[22];const float* bn2_v = (const float*)d_in[23];
    const float* Wr2 = (const float*)d_in[24];  const float* br2 = (const float*)d_in[25];
    const int* src = (const int*)d_in[26];
    const int* dst = (const int*)d_in[27];
    const int* evid = (const int*)d_in[28];
    const int* hids = (const int*)d_in[29];
    const int* rids = (const int*)d_in[30];
    const int* tids = (const int*)d_in[31];
    const int* upd = (const int*)d_in[32];
    const int* ihead = (const int*)d_in[33];

    float* ws = (float*)d_ws;
    float* C1   = ws;                      // 20000*192
    float* A2   = C1 + 3840000;            // 20000*192
    float* E1   = A2 + 3840000;            // 500*256
    unsigned short* Bn1 = (unsigned short*)(E1 + 128000);  // 256*256 bf16
    unsigned short* Bn2 = Bn1 + 65536;                     // 256*192 bf16
    float* s1   = (float*)(Bn2 + 49152);   // 64
    float* t1   = s1 + 64;                 // 64
    float* s2   = t1 + 64;                 // 256
    float* t2   = s2 + 256;                // 256
    float* tvec = t2 + 256;                // 32*256

    unsigned* R = (unsigned*)(tvec + 8192);// 2*NE packed records
    int* cnt2   = (int*)(R + 2 * NE);      // TOT2
    int* offc2  = cnt2 + TOT2;             // TOT2+1
    int* cur2   = offc2 + TOT2 + 1;        // TOT2
    int* bsum   = cur2 + TOT2;             // NB2

    float* hn    = (float*)d_out;                       // 20000*256
    float* score = hn + (size_t)NN * EMBD;              // 32*20000

    hipMemsetAsync(cnt2, 0, (size_t)TOT2 * 4, stream);

    k_buildBn<<<NBLK_BN + 2, 256, 0, stream>>>(
        W_O1, W_I1, W_S1, Wr1, W_O2, W_I2, W_S2, Bn1, Bn2,
        b_O1, b_I1, b_S1, bn1_g, bn1_b, bn1_m, bn1_v,
        b_O2, b_I2, b_S2, bn2_g, bn2_b, bn2_m, bn2_v,
        s1, t1, s2, t2);

    // partitioned CSR build
    k_hist<<<(NE + 255) / 256, 256, 0, stream>>>(src, dst, cnt2);
    k_scanA<<<NB2, 256, 0, stream>>>(cnt2, bsum);
    k_scanB<<<1, 64, 0, stream>>>(bsum, NB2);
    k_scanC<<<NB2, 256, 0, stream>>>(cnt2, bsum, offc2, cur2);
    k_scatter<<<(NE + 255) / 256, 256, 0, stream>>>(src, dst, evid, cur2, R);

    // C1 = node_embs @ Bn1[0:192]^T   (M=20000, K=256)
    gemm_mfma<<<dim3(313, 3), 256, 0, stream>>>(node_embs, NN, 256, 256, Bn1,
                                                C1, 192, 0, nullptr, nullptr, nullptr, nullptr);
    // E1 = edge_embs @ Bn1^T, fused er1 on cols [192,256)   (M=500, K=256)
    gemm_mfma<<<dim3(8, 4), 256, 0, stream>>>(edge_embs, NR, 256, 256, Bn1,
                                              E1, 256, 1, br1, nullptr, nullptr, nullptr);

    // layer-1 aggregation + combine (writes h1 into A2 cols [128,192))
    k_gather1<<<NN / 4, 256, 0, stream>>>(offc2, R, C1, E1, s1, t1, A2);
    // layer-2 aggregation (writes A2 cols [0,128))
    k_gather2<<<NN / 4, 256, 0, stream>>>(offc2, R, A2, E1, A2);

    // hn = tanh((A2 @ Bn2^T) * s2 + t2)  (or node_embs if !upd)  (M=20000, K=192)
    gemm_mfma<<<dim3(313, 4), 256, 0, stream>>>(A2, NN, 192, 192, Bn2,
                                                hn, 256, 2, s2, t2, node_embs, upd);

    k_rels<<<BQ, 64, 0, stream>>>(edge_embs, Wr1, br1, Wr2, br2,
                                  hids, rids, tids, ihead, hn, tvec);
    k_score<<<(BQ * (NN / BQ)) / 4, 256, 0, stream>>>(hn, tvec, score);
}